// Round 2
// baseline (1946.316 us; speedup 1.0000x reference)
//
#include <hip/hip_runtime.h>
#include <hip/hip_fp16.h>
#include <hip/hip_bf16.h>

// Packed bidirectional 2-layer LSTM for MI355X.
// Phases: setup (offsets/lengths) -> convert (bf16 casts, bias sum)
//   -> per layer: GEMM gates = x@Wih^T + b (bf16 MFMA) -> per-(seq,dir) recurrence.
// Recurrence v2: within-wave slice reduction (ds_swizzle/shfl), redundant epilogue
// across the 4 slice-replica lanes, double-buffered h, ONE barrier per step.

#define CELL 128
#define GATES 512
#define DIN 256
#define NB 64

typedef float f4_t __attribute__((ext_vector_type(4)));
typedef short bf8_t __attribute__((ext_vector_type(8)));
typedef _Float16 h2_t __attribute__((ext_vector_type(2)));

static __device__ __forceinline__ unsigned short f32_bf16(float f) {
  union { float f; unsigned int u; } v; v.f = f;
  unsigned int u = v.u;
  return (unsigned short)((u + 0x7fffu + ((u >> 16) & 1u)) >> 16);
}

// ---------------- setup: exclusive cumsum + per-seq lengths ----------------
__global__ void k_setup(const int* __restrict__ bs, int T,
                        int* __restrict__ offsets, int* __restrict__ lengths) {
  __shared__ int sbs[1024];
  int t = threadIdx.x;
  sbs[t] = (t < T) ? bs[t] : 0;
  __syncthreads();
  int sum = 0;
  for (int i = 0; i < t; ++i) sum += sbs[i];
  if (t < T) offsets[t] = sum;
  if (t < NB) {
    int c = 0;
    for (int i = 0; i < T; ++i) c += (sbs[i] > t) ? 1 : 0;
    lengths[t] = c;
  }
}

// ---------------- convert: x->bf16, W_ih->bf16, bias sum ----------------
__global__ void k_convert(const float* __restrict__ x, unsigned short* __restrict__ xb, int nx,
                          const float* __restrict__ wih, unsigned short* __restrict__ wb, int nw,
                          const float* __restrict__ bih, const float* __restrict__ bhh,
                          float* __restrict__ bsum, int nb2) {
  int stride = gridDim.x * blockDim.x;
  int i0 = blockIdx.x * blockDim.x + threadIdx.x;
  for (int i = i0; i < nx; i += stride) xb[i] = f32_bf16(x[i]);
  for (int i = i0; i < nw; i += stride) wb[i] = f32_bf16(wih[i]);
  for (int i = i0; i < nb2; i += stride) bsum[i] = bih[i] + bhh[i];
}

// ---------------- GEMM: C(M,1024) f16 = A(M,256)bf16 @ W(rows lbase..+1023)^T + bias ----
__global__ __launch_bounds__(256) void k_gemm(
    const unsigned short* __restrict__ A,
    const unsigned short* __restrict__ W,   // (2048,256) bf16
    const float* __restrict__ bsum,         // (2048,)
    __half* __restrict__ C,
    int M, int lbase) {
  __shared__ __align__(16) unsigned short As[128 * 64];
  __shared__ __align__(16) unsigned short Bs[128 * 64];
  const int tid = threadIdx.x;
  const int lane = tid & 63;
  const int wave = tid >> 6;
  const int wm = wave >> 1, wn = wave & 1;   // 2x2 wave grid, 64x64 per wave
  const int m0 = blockIdx.x * 128;
  const int n0 = blockIdx.y * 128;

  f4_t acc[4][4];
#pragma unroll
  for (int i = 0; i < 4; ++i)
#pragma unroll
    for (int j = 0; j < 4; ++j) acc[i][j] = (f4_t){0.f, 0.f, 0.f, 0.f};

  for (int kt = 0; kt < 256; kt += 64) {
    // stage A,B tiles: linear LDS dest, inverse-XOR-swizzled global source (rule #21)
#pragma unroll
    for (int it = 0; it < 4; ++it) {
      int idx = it * 256 + tid;        // 16B units
      int row = idx >> 3;
      int gslot = (idx & 7) ^ (row & 7);
      int grow = m0 + row; if (grow > M - 1) grow = M - 1;
      __builtin_amdgcn_global_load_lds(
          (const __attribute__((address_space(1))) unsigned int*)(A + (size_t)grow * 256 + kt + gslot * 8),
          (__attribute__((address_space(3))) unsigned int*)(As + idx * 8), 16, 0, 0);
    }
#pragma unroll
    for (int it = 0; it < 4; ++it) {
      int idx = it * 256 + tid;
      int row = idx >> 3;
      int gslot = (idx & 7) ^ (row & 7);
      __builtin_amdgcn_global_load_lds(
          (const __attribute__((address_space(1))) unsigned int*)(W + (size_t)(lbase + n0 + row) * 256 + kt + gslot * 8),
          (__attribute__((address_space(3))) unsigned int*)(Bs + idx * 8), 16, 0, 0);
    }
    asm volatile("s_waitcnt vmcnt(0)" ::: "memory");
    __syncthreads();
#pragma unroll
    for (int kk = 0; kk < 2; ++kk) {
      bf8_t af[4], bfv[4];
#pragma unroll
      for (int i = 0; i < 4; ++i) {
        int arow = wm * 64 + i * 16 + (lane & 15);
        int aslot = (kk * 4 + (lane >> 4)) ^ (arow & 7);
        af[i] = *(const bf8_t*)(As + arow * 64 + aslot * 8);
        int brow = wn * 64 + i * 16 + (lane & 15);
        int bslot = (kk * 4 + (lane >> 4)) ^ (brow & 7);
        bfv[i] = *(const bf8_t*)(Bs + brow * 64 + bslot * 8);
      }
#pragma unroll
      for (int i = 0; i < 4; ++i)
#pragma unroll
        for (int j = 0; j < 4; ++j)
          acc[i][j] = __builtin_amdgcn_mfma_f32_16x16x32_bf16(af[i], bfv[j], acc[i][j], 0, 0, 0);
    }
    __syncthreads();
  }
  // epilogue: C[row][col], row=(lane>>4)*4+r, col=lane&15 (m89 mapping)
#pragma unroll
  for (int i = 0; i < 4; ++i) {
#pragma unroll
    for (int j = 0; j < 4; ++j) {
      int col = n0 + wn * 64 + j * 16 + (lane & 15);
      float bv = bsum[lbase + col];
#pragma unroll
      for (int r = 0; r < 4; ++r) {
        int row = m0 + wm * 64 + i * 16 + (lane >> 4) * 4 + r;
        if (row < M) C[(size_t)row * 1024 + col] = (__half)(acc[i][j][r] + bv);
      }
    }
  }
}

// ---------------- recurrence: one workgroup per (seq, dir) chain ----------------
#if defined(__has_builtin)
#if __has_builtin(__builtin_amdgcn_fdot2)
#define HAVE_FDOT2 1
#endif
#endif

static __device__ __forceinline__ float fdot2(h2_t a, h2_t b, float c) {
#ifdef HAVE_FDOT2
  return __builtin_amdgcn_fdot2(a, b, c, false);
#else
  return c + (float)a[0] * (float)b[0] + (float)a[1] * (float)b[1];
#endif
}
static __device__ __forceinline__ float sigm(float x) { return 1.f / (1.f + __expf(-x)); }
static __device__ __forceinline__ float tanh_(float x) { return 1.f - 2.f / (1.f + __expf(2.f * x)); }

// xor-16 across lanes (within 32-lane half): ds_swizzle BitMode, offset 0x401F
static __device__ __forceinline__ float red16(float v) {
  return v + __int_as_float(__builtin_amdgcn_ds_swizzle(__float_as_int(v), 0x401F));
}
static __device__ __forceinline__ float red32(float v) {
  return v + __shfl_xor(v, 32, 64);
}

template <int LAYER>
__global__ __launch_bounds__(512) void k_rec(
    const __half* __restrict__ gates,     // (TOTAL,1024): [tok][d*512+g]
    const int* __restrict__ offsets,      // (T,)
    const int* __restrict__ lengths,      // (NB,)
    const float* __restrict__ h0,         // (4,NB,CELL)
    const float* __restrict__ c0,
    const float* __restrict__ Whh,        // (4,512,128) f32
    unsigned short* __restrict__ y1,      // (TOTAL,256) bf16 (LAYER==0)
    float* __restrict__ outp,             // (TOTAL,256) f32  (LAYER==1)
    float* __restrict__ hn, float* __restrict__ cn,
    int T) {
  const int b = blockIdx.x >> 1;
  const int d = blockIdx.x & 1;
  const int k = 2 * LAYER + d;
  const int tid = threadIdx.x;
  const int lane = tid & 63;
  const int wave = tid >> 6;
  const int q = wave * 16 + (lane & 15);  // cell index 0..127 (per wave: 16 cells)
  const int s = lane >> 4;                // k-slice 0..3 (32 k each)
  const int L = lengths[b];

  __shared__ __align__(16) __half hb[2][CELL];  // double-buffered h
  __shared__ int toks[1024];

  for (int t = tid; t < T; t += 512) toks[t] = offsets[t] + b;

  // Per-thread weights: gate rows {q, 128+q, 256+q, 384+q}, k in [32s,32s+32), f16 pairs.
  h2_t wp[4][16];
  {
    const float* Wb = Whh + (size_t)k * GATES * CELL;
#pragma unroll
    for (int gi = 0; gi < 4; ++gi) {
      const float2* rowp = (const float2*)(Wb + (size_t)(gi * CELL + q) * CELL + s * 32);
#pragma unroll
      for (int j = 0; j < 16; ++j) {
        float2 w = rowp[j];
        h2_t p; p[0] = (_Float16)w.x; p[1] = (_Float16)w.y;
        wp[gi][j] = p;
      }
    }
  }

  // all replica lanes hold their cell's state (identical arithmetic -> identical values)
  float hcur = h0[(size_t)k * NB * CELL + b * CELL + q];
  float ccur = c0[(size_t)k * NB * CELL + b * CELL + q];
  if (s == 0) hb[0][q] = (__half)hcur;
  __syncthreads();   // toks + initial h visible

  // prefetch first step's gate-x (each lane: its own cell, replicated -> coalesced)
  __half gx0 = __half(0.f), gx1 = __half(0.f), gx2 = __half(0.f), gx3 = __half(0.f);
  int tokc = 0;
  if (L > 0) {
    tokc = toks[d ? (L - 1) : 0];
    const __half* gp = gates + (size_t)tokc * 1024 + d * GATES + q;
    gx0 = gp[0]; gx1 = gp[CELL]; gx2 = gp[2 * CELL]; gx3 = gp[3 * CELL];
  }

  int p = 0;
  for (int n = 0; n < L; ++n) {
    // prefetch next step's gate-x (independent of this step's chain)
    int tokn = tokc;
    if (n + 1 < L) tokn = toks[d ? (L - 2 - n) : (n + 1)];
    __half gn0, gn1, gn2, gn3;
    {
      const __half* gp = gates + (size_t)tokn * 1024 + d * GATES + q;
      gn0 = gp[0]; gn1 = gp[CELL]; gn2 = gp[2 * CELL]; gn3 = gp[3 * CELL];
    }

    // dot stage: 4 gates x 32 k as 16 dot2 each
    const h2_t* hsh = (const h2_t*)hb[p];
    h2_t hp[16];
#pragma unroll
    for (int j = 0; j < 16; ++j) hp[j] = hsh[s * 16 + j];
    float a0 = 0.f, a1 = 0.f, a2 = 0.f, a3 = 0.f;
#pragma unroll
    for (int j = 0; j < 16; ++j) {
      a0 = fdot2(wp[0][j], hp[j], a0);
      a1 = fdot2(wp[1][j], hp[j], a1);
      a2 = fdot2(wp[2][j], hp[j], a2);
      a3 = fdot2(wp[3][j], hp[j], a3);
    }
    // within-wave butterfly over the 4 k-slices (lanes l, l^16, l^32, l^48)
    a0 = red32(red16(a0));
    a1 = red32(red16(a1));
    a2 = red32(red16(a2));
    a3 = red32(red16(a3));

    // epilogue: ALL lanes (4x replicated per cell, branch-free)
    float gi = a0 + __half2float(gx0);
    float gf = a1 + __half2float(gx1);
    float gg = a2 + __half2float(gx2);
    float go = a3 + __half2float(gx3);
    float fi = sigm(gi), ff = sigm(gf), fg = tanh_(gg), fo = sigm(go);
    ccur = ff * ccur + fi * fg;
    hcur = fo * tanh_(ccur);

    if (s == 0) {
      hb[p ^ 1][q] = (__half)hcur;
      if (LAYER == 0)
        y1[(size_t)tokc * 256 + d * CELL + q] = f32_bf16(hcur);
      else
        outp[(size_t)tokc * 256 + d * CELL + q] = hcur;
    }
    __syncthreads();   // new h visible to all waves
    p ^= 1;
    gx0 = gn0; gx1 = gn1; gx2 = gn2; gx3 = gn3;
    tokc = tokn;
  }
  if (s == 0) {
    hn[(size_t)k * NB * CELL + b * CELL + q] = hcur;
    cn[(size_t)k * NB * CELL + b * CELL + q] = ccur;
  }
}

// ---------------- launch ----------------
extern "C" void kernel_launch(void* const* d_in, const int* in_sizes, int n_in,
                              void* d_out, int out_size, void* d_ws, size_t ws_size,
                              hipStream_t stream) {
  const float* x   = (const float*)d_in[0];
  const int*   bs  = (const int*)d_in[1];
  const float* h0  = (const float*)d_in[2];
  const float* c0  = (const float*)d_in[3];
  const float* wih = (const float*)d_in[4];
  const float* whh = (const float*)d_in[5];
  const float* bih = (const float*)d_in[6];
  const float* bhh = (const float*)d_in[7];
  const int TOTAL = in_sizes[0] / DIN;
  const int T = in_sizes[1];

  char* ws = (char*)d_ws;
  size_t off = 0;
  auto alloc = [&](size_t bytes) {
    void* p = ws + off;
    off = (off + bytes + 255) & ~(size_t)255;
    return p;
  };
  int* offsets        = (int*)alloc((size_t)T * 4);
  int* lengths        = (int*)alloc(NB * 4);
  float* bsum         = (float*)alloc(2048 * 4);
  unsigned short* wb  = (unsigned short*)alloc((size_t)2048 * 256 * 2);
  unsigned short* xb  = (unsigned short*)alloc((size_t)TOTAL * 256 * 2);
  unsigned short* y1  = (unsigned short*)alloc((size_t)TOTAL * 256 * 2);
  __half* gates       = (__half*)alloc((size_t)TOTAL * 1024 * 2);
  // total ~153 MB; assumed <= ws_size

  float* outp = (float*)d_out;
  float* hn = outp + (size_t)TOTAL * 256;
  float* cn = hn + 4 * NB * CELL;

  k_setup<<<1, 1024, 0, stream>>>(bs, T, offsets, lengths);
  k_convert<<<1024, 256, 0, stream>>>(x, xb, TOTAL * 256,
                                      wih, wb, 4 * GATES * DIN,
                                      bih, bhh, bsum, 2048);
  dim3 ggrid((TOTAL + 127) / 128, 8);
  // layer 0
  k_gemm<<<ggrid, 256, 0, stream>>>(xb, wb, bsum, gates, TOTAL, 0);
  k_rec<0><<<NB * 2, 512, 0, stream>>>(gates, offsets, lengths, h0, c0, whh,
                                       y1, nullptr, hn, cn, T);
  // layer 1
  k_gemm<<<ggrid, 256, 0, stream>>>(y1, wb, bsum, gates, TOTAL, 1024);
  k_rec<1><<<NB * 2, 512, 0, stream>>>(gates, offsets, lengths, h0, c0, whh,
                                       nullptr, outp, hn, cn, T);
}

// Round 3
// 1911.812 us; speedup vs baseline: 1.0180x; 1.0180x over previous
//
#include <hip/hip_runtime.h>
#include <hip/hip_fp16.h>
#include <hip/hip_bf16.h>

// Packed bidirectional 2-layer LSTM for MI355X.
// v3: recurrence with 4 waves/chain, single-stage shfl reduce, gate tensor in
// [tok][d*512 + q*4 + gate] layout (one dwordx2 per lane per step), distance-2
// prefetch into statically-named register slots, ping-pong h in LDS, ONE
// barrier per step.

#define CELL 128
#define GATES 512
#define DIN 256
#define NB 64

typedef float f4_t __attribute__((ext_vector_type(4)));
typedef short bf8_t __attribute__((ext_vector_type(8)));
typedef _Float16 h2_t __attribute__((ext_vector_type(2)));

static __device__ __forceinline__ unsigned short f32_bf16(float f) {
  union { float f; unsigned int u; } v; v.f = f;
  unsigned int u = v.u;
  return (unsigned short)((u + 0x7fffu + ((u >> 16) & 1u)) >> 16);
}

// ---------------- setup: exclusive cumsum + per-seq lengths ----------------
__global__ void k_setup(const int* __restrict__ bs, int T,
                        int* __restrict__ offsets, int* __restrict__ lengths) {
  __shared__ int sbs[1024];
  int t = threadIdx.x;
  sbs[t] = (t < T) ? bs[t] : 0;
  __syncthreads();
  int sum = 0;
  for (int i = 0; i < t; ++i) sum += sbs[i];
  if (t < T) offsets[t] = sum;
  if (t < NB) {
    int c = 0;
    for (int i = 0; i < T; ++i) c += (sbs[i] > t) ? 1 : 0;
    lengths[t] = c;
  }
}

// ---------------- convert: x->bf16, W_ih->bf16, bias sum ----------------
__global__ void k_convert(const float* __restrict__ x, unsigned short* __restrict__ xb, int nx,
                          const float* __restrict__ wih, unsigned short* __restrict__ wb, int nw,
                          const float* __restrict__ bih, const float* __restrict__ bhh,
                          float* __restrict__ bsum, int nb2) {
  int stride = gridDim.x * blockDim.x;
  int i0 = blockIdx.x * blockDim.x + threadIdx.x;
  for (int i = i0; i < nx; i += stride) xb[i] = f32_bf16(x[i]);
  for (int i = i0; i < nw; i += stride) wb[i] = f32_bf16(wih[i]);
  for (int i = i0; i < nb2; i += stride) bsum[i] = bih[i] + bhh[i];
}

// ---------------- GEMM: gates(M,1024) f16 = A(M,256)bf16 @ W^T + bias ----
// Output layout per row: [d*512 + q*4 + gate]  (gate-major -> cell-major remap)
__global__ __launch_bounds__(256) void k_gemm(
    const unsigned short* __restrict__ A,
    const unsigned short* __restrict__ W,   // (2048,256) bf16
    const float* __restrict__ bsum,         // (2048,)
    __half* __restrict__ C,
    int M, int lbase) {
  __shared__ __align__(16) unsigned short As[128 * 64];
  __shared__ __align__(16) unsigned short Bs[128 * 64];
  const int tid = threadIdx.x;
  const int lane = tid & 63;
  const int wave = tid >> 6;
  const int wm = wave >> 1, wn = wave & 1;   // 2x2 wave grid, 64x64 per wave
  const int m0 = blockIdx.x * 128;
  const int n0 = blockIdx.y * 128;

  f4_t acc[4][4];
#pragma unroll
  for (int i = 0; i < 4; ++i)
#pragma unroll
    for (int j = 0; j < 4; ++j) acc[i][j] = (f4_t){0.f, 0.f, 0.f, 0.f};

  for (int kt = 0; kt < 256; kt += 64) {
    // stage A,B tiles: linear LDS dest, inverse-XOR-swizzled global source (rule #21)
#pragma unroll
    for (int it = 0; it < 4; ++it) {
      int idx = it * 256 + tid;        // 16B units
      int row = idx >> 3;
      int gslot = (idx & 7) ^ (row & 7);
      int grow = m0 + row; if (grow > M - 1) grow = M - 1;
      __builtin_amdgcn_global_load_lds(
          (const __attribute__((address_space(1))) unsigned int*)(A + (size_t)grow * 256 + kt + gslot * 8),
          (__attribute__((address_space(3))) unsigned int*)(As + idx * 8), 16, 0, 0);
    }
#pragma unroll
    for (int it = 0; it < 4; ++it) {
      int idx = it * 256 + tid;
      int row = idx >> 3;
      int gslot = (idx & 7) ^ (row & 7);
      __builtin_amdgcn_global_load_lds(
          (const __attribute__((address_space(1))) unsigned int*)(W + (size_t)(lbase + n0 + row) * 256 + kt + gslot * 8),
          (__attribute__((address_space(3))) unsigned int*)(Bs + idx * 8), 16, 0, 0);
    }
    asm volatile("s_waitcnt vmcnt(0)" ::: "memory");
    __syncthreads();
#pragma unroll
    for (int kk = 0; kk < 2; ++kk) {
      bf8_t af[4], bfv[4];
#pragma unroll
      for (int i = 0; i < 4; ++i) {
        int arow = wm * 64 + i * 16 + (lane & 15);
        int aslot = (kk * 4 + (lane >> 4)) ^ (arow & 7);
        af[i] = *(const bf8_t*)(As + arow * 64 + aslot * 8);
        int brow = wn * 64 + i * 16 + (lane & 15);
        int bslot = (kk * 4 + (lane >> 4)) ^ (brow & 7);
        bfv[i] = *(const bf8_t*)(Bs + brow * 64 + bslot * 8);
      }
#pragma unroll
      for (int i = 0; i < 4; ++i)
#pragma unroll
        for (int j = 0; j < 4; ++j)
          acc[i][j] = __builtin_amdgcn_mfma_f32_16x16x32_bf16(af[i], bfv[j], acc[i][j], 0, 0, 0);
    }
    __syncthreads();
  }
  // epilogue: C/D map row=(lane>>4)*4+r, col=lane&15 (m89), remap col->gate layout
#pragma unroll
  for (int i = 0; i < 4; ++i) {
#pragma unroll
    for (int j = 0; j < 4; ++j) {
      int col = n0 + wn * 64 + j * 16 + (lane & 15);
      float bv = bsum[lbase + col];
      int d_ = col >> 9, gate_ = (col >> 7) & 3, q_ = col & 127;
      int ncol = d_ * 512 + q_ * 4 + gate_;
#pragma unroll
      for (int r = 0; r < 4; ++r) {
        int row = m0 + wm * 64 + i * 16 + (lane >> 4) * 4 + r;
        if (row < M) C[(size_t)row * 1024 + ncol] = (__half)(acc[i][j][r] + bv);
      }
    }
  }
}

// ---------------- recurrence: one workgroup (4 waves) per (seq, dir) chain ----------------
#if defined(__has_builtin)
#if __has_builtin(__builtin_amdgcn_fdot2)
#define HAVE_FDOT2 1
#endif
#endif

static __device__ __forceinline__ float fdot2(h2_t a, h2_t b, float c) {
#ifdef HAVE_FDOT2
  return __builtin_amdgcn_fdot2(a, b, c, false);
#else
  return c + (float)a[0] * (float)b[0] + (float)a[1] * (float)b[1];
#endif
}
static __device__ __forceinline__ float sigm(float x) { return 1.f / (1.f + __expf(-x)); }
static __device__ __forceinline__ float tanh_(float x) { return 1.f - 2.f / (1.f + __expf(2.f * x)); }

template <int LAYER>
__global__ __launch_bounds__(256) void k_rec(
    const __half* __restrict__ gates,     // (TOTAL,1024): [tok][d*512 + q*4 + gate]
    const int* __restrict__ offsets,      // (T,)
    const int* __restrict__ lengths,      // (NB,)
    const float* __restrict__ h0,         // (4,NB,CELL)
    const float* __restrict__ c0,
    const float* __restrict__ Whh,        // (4,512,128) f32
    unsigned short* __restrict__ y1,      // (TOTAL,256) bf16 (LAYER==0)
    float* __restrict__ outp,             // (TOTAL,256) f32  (LAYER==1)
    float* __restrict__ hn, float* __restrict__ cn,
    int T) {
  const int b = blockIdx.x >> 1;
  const int d = blockIdx.x & 1;
  const int k = 2 * LAYER + d;
  const int tid = threadIdx.x;
  const int lane = tid & 63;
  const int wave = tid >> 6;
  const int q = wave * 32 + (lane & 31);  // cell 0..127; each wave owns 32 cells
  const int s = lane >> 5;                // k-slice 0..1 (64 k each)
  const int L = lengths[b];

  __shared__ __align__(16) __half hb[2][CELL];  // ping-pong h
  __shared__ int toks[1024];

  for (int t = tid; t < T; t += 256) toks[t] = offsets[t] + b;

  // Per-thread weights: gate rows {q,128+q,256+q,384+q}, k in [64s, 64s+64), f16 pairs.
  h2_t wp[4][32];
  {
    const float* Wb = Whh + (size_t)k * GATES * CELL;
#pragma unroll
    for (int gi = 0; gi < 4; ++gi) {
      const float2* rowp = (const float2*)(Wb + (size_t)(gi * CELL + q) * CELL + s * 64);
#pragma unroll
      for (int j = 0; j < 32; ++j) {
        float2 w = rowp[j];
        h2_t pr; pr[0] = (_Float16)w.x; pr[1] = (_Float16)w.y;
        wp[gi][j] = pr;
      }
    }
  }

  float hcur = h0[(size_t)k * NB * CELL + b * CELL + q];
  float ccur = c0[(size_t)k * NB * CELL + b * CELL + q];
  if (s == 0) hb[0][q] = (__half)hcur;
  __syncthreads();   // toks + initial h visible

  const __half* gbase = gates + (size_t)d * 512 + (size_t)q * 4;
  auto tok_at = [&](int m) { int mm = (m < L) ? m : (L - 1); return toks[d ? (L - 1 - mm) : mm]; };
  auto gload = [&](int m) { return *(const uint2*)(gbase + (size_t)tok_at(m) * 1024); };

  // distance-2 prefetch into two statically named slots (no register copies)
  uint2 gA = (L > 0) ? gload(0) : make_uint2(0, 0);
  uint2 gB = (L > 1) ? gload(1) : gA;

  int p = 0;
  auto body = [&](int n, uint2& gcur) {
    // dot stage: 4 gates x 64 k, two 16-deep chains per gate
    const h2_t* hsh = (const h2_t*)(&hb[p][0]) + s * 32;
    h2_t hp[32];
#pragma unroll
    for (int j = 0; j < 32; ++j) hp[j] = hsh[j];
    float x00 = 0.f, x01 = 0.f, x10 = 0.f, x11 = 0.f;
    float x20 = 0.f, x21 = 0.f, x30 = 0.f, x31 = 0.f;
#pragma unroll
    for (int j = 0; j < 16; ++j) {
      x00 = fdot2(wp[0][j], hp[j], x00); x01 = fdot2(wp[0][j + 16], hp[j + 16], x01);
      x10 = fdot2(wp[1][j], hp[j], x10); x11 = fdot2(wp[1][j + 16], hp[j + 16], x11);
      x20 = fdot2(wp[2][j], hp[j], x20); x21 = fdot2(wp[2][j + 16], hp[j + 16], x21);
      x30 = fdot2(wp[3][j], hp[j], x30); x31 = fdot2(wp[3][j + 16], hp[j + 16], x31);
    }
    float f0 = x00 + x01, f1 = x10 + x11, f2 = x20 + x21, f3 = x30 + x31;
    // single-stage reduce across the 2 k-slices (lanes l <-> l^32)
    f0 += __shfl_xor(f0, 32, 64);
    f1 += __shfl_xor(f1, 32, 64);
    f2 += __shfl_xor(f2, 32, 64);
    f3 += __shfl_xor(f3, 32, 64);

    // epilogue (replicated on both slice lanes, branch-free)
    union { uint2 u; __half h[4]; } gg; gg.u = gcur;
    float vi = f0 + (float)gg.h[0];
    float vf = f1 + (float)gg.h[1];
    float vg = f2 + (float)gg.h[2];
    float vo = f3 + (float)gg.h[3];
    float fi = sigm(vi), ff = sigm(vf), fg = tanh_(vg), fo = sigm(vo);
    ccur = ff * ccur + fi * fg;
    hcur = fo * tanh_(ccur);

    int tokc = tok_at(n);
    if (s == 0) {
      hb[p ^ 1][q] = (__half)hcur;
      if (LAYER == 0)
        y1[(size_t)tokc * 256 + d * CELL + q] = f32_bf16(hcur);
      else
        outp[(size_t)tokc * 256 + d * CELL + q] = hcur;
    }
    // prefetch step n+2 into the slot just consumed; vmcnt wait lands at its use
    gcur = gload(n + 2);
    __syncthreads();   // new h visible; also fences hb[p] reads before next overwrite
    p ^= 1;
  };

  int n = 0;
  while (n + 1 < L) { body(n, gA); body(n + 1, gB); n += 2; }
  if (n < L) body(n, gA);

  if (s == 0) {
    hn[(size_t)k * NB * CELL + b * CELL + q] = hcur;
    cn[(size_t)k * NB * CELL + b * CELL + q] = ccur;
  }
}

// ---------------- launch ----------------
extern "C" void kernel_launch(void* const* d_in, const int* in_sizes, int n_in,
                              void* d_out, int out_size, void* d_ws, size_t ws_size,
                              hipStream_t stream) {
  const float* x   = (const float*)d_in[0];
  const int*   bs  = (const int*)d_in[1];
  const float* h0  = (const float*)d_in[2];
  const float* c0  = (const float*)d_in[3];
  const float* wih = (const float*)d_in[4];
  const float* whh = (const float*)d_in[5];
  const float* bih = (const float*)d_in[6];
  const float* bhh = (const float*)d_in[7];
  const int TOTAL = in_sizes[0] / DIN;
  const int T = in_sizes[1];

  char* ws = (char*)d_ws;
  size_t off = 0;
  auto alloc = [&](size_t bytes) {
    void* p = ws + off;
    off = (off + bytes + 255) & ~(size_t)255;
    return p;
  };
  int* offsets        = (int*)alloc((size_t)T * 4);
  int* lengths        = (int*)alloc(NB * 4);
  float* bsum         = (float*)alloc(2048 * 4);
  unsigned short* wb  = (unsigned short*)alloc((size_t)2048 * 256 * 2);
  unsigned short* xb  = (unsigned short*)alloc((size_t)TOTAL * 256 * 2);
  unsigned short* y1  = (unsigned short*)alloc((size_t)TOTAL * 256 * 2);
  __half* gates       = (__half*)alloc((size_t)TOTAL * 1024 * 2);
  // total ~153 MB; assumed <= ws_size

  float* outp = (float*)d_out;
  float* hn = outp + (size_t)TOTAL * 256;
  float* cn = hn + 4 * NB * CELL;

  k_setup<<<1, 1024, 0, stream>>>(bs, T, offsets, lengths);
  k_convert<<<1024, 256, 0, stream>>>(x, xb, TOTAL * 256,
                                      wih, wb, 4 * GATES * DIN,
                                      bih, bhh, bsum, 2048);
  dim3 ggrid((TOTAL + 127) / 128, 8);
  // layer 0
  k_gemm<<<ggrid, 256, 0, stream>>>(xb, wb, bsum, gates, TOTAL, 0);
  k_rec<0><<<NB * 2, 256, 0, stream>>>(gates, offsets, lengths, h0, c0, whh,
                                       y1, nullptr, hn, cn, T);
  // layer 1
  k_gemm<<<ggrid, 256, 0, stream>>>(y1, wb, bsum, gates, TOTAL, 1024);
  k_rec<1><<<NB * 2, 256, 0, stream>>>(gates, offsets, lengths, h0, c0, whh,
                                       nullptr, outp, hn, cn, T);
}

// Round 4
// 1753.717 us; speedup vs baseline: 1.1098x; 1.0901x over previous
//
#include <hip/hip_runtime.h>
#include <hip/hip_fp16.h>
#include <hip/hip_bf16.h>

// Packed bidirectional 2-layer LSTM for MI355X.
// v4: v3 + the key fix — recurrence barriers are raw s_barrier with
// lgkmcnt-only waits (NO vmcnt drain). __syncthreads() drains vmcnt(0),
// which put the gate prefetch + output store on the serial critical path
// every step (~1400 cy/step of exposed memory latency across v1-v3).
// Also: v_rcp_f32-based sigmoid/tanh (avoids the 3-op IEEE divide).

#define CELL 128
#define GATES 512
#define DIN 256
#define NB 64

typedef float f4_t __attribute__((ext_vector_type(4)));
typedef short bf8_t __attribute__((ext_vector_type(8)));
typedef _Float16 h2_t __attribute__((ext_vector_type(2)));

static __device__ __forceinline__ unsigned short f32_bf16(float f) {
  union { float f; unsigned int u; } v; v.f = f;
  unsigned int u = v.u;
  return (unsigned short)((u + 0x7fffu + ((u >> 16) & 1u)) >> 16);
}

// LDS-ordering barrier WITHOUT the vmcnt(0) drain __syncthreads would emit.
static __device__ __forceinline__ void barrier_lds() {
  asm volatile("s_waitcnt lgkmcnt(0)" ::: "memory");
  __builtin_amdgcn_s_barrier();
}

// ---------------- setup: exclusive cumsum + per-seq lengths ----------------
__global__ void k_setup(const int* __restrict__ bs, int T,
                        int* __restrict__ offsets, int* __restrict__ lengths) {
  __shared__ int sbs[1024];
  int t = threadIdx.x;
  sbs[t] = (t < T) ? bs[t] : 0;
  __syncthreads();
  int sum = 0;
  for (int i = 0; i < t; ++i) sum += sbs[i];
  if (t < T) offsets[t] = sum;
  if (t < NB) {
    int c = 0;
    for (int i = 0; i < T; ++i) c += (sbs[i] > t) ? 1 : 0;
    lengths[t] = c;
  }
}

// ---------------- convert: x->bf16, W_ih->bf16, bias sum ----------------
__global__ void k_convert(const float* __restrict__ x, unsigned short* __restrict__ xb, int nx,
                          const float* __restrict__ wih, unsigned short* __restrict__ wb, int nw,
                          const float* __restrict__ bih, const float* __restrict__ bhh,
                          float* __restrict__ bsum, int nb2) {
  int stride = gridDim.x * blockDim.x;
  int i0 = blockIdx.x * blockDim.x + threadIdx.x;
  for (int i = i0; i < nx; i += stride) xb[i] = f32_bf16(x[i]);
  for (int i = i0; i < nw; i += stride) wb[i] = f32_bf16(wih[i]);
  for (int i = i0; i < nb2; i += stride) bsum[i] = bih[i] + bhh[i];
}

// ---------------- GEMM: gates(M,1024) f16 = A(M,256)bf16 @ W^T + bias ----
// Output layout per row: [d*512 + q*4 + gate]  (gate-major -> cell-major remap)
__global__ __launch_bounds__(256) void k_gemm(
    const unsigned short* __restrict__ A,
    const unsigned short* __restrict__ W,   // (2048,256) bf16
    const float* __restrict__ bsum,         // (2048,)
    __half* __restrict__ C,
    int M, int lbase) {
  __shared__ __align__(16) unsigned short As[128 * 64];
  __shared__ __align__(16) unsigned short Bs[128 * 64];
  const int tid = threadIdx.x;
  const int lane = tid & 63;
  const int wave = tid >> 6;
  const int wm = wave >> 1, wn = wave & 1;   // 2x2 wave grid, 64x64 per wave
  const int m0 = blockIdx.x * 128;
  const int n0 = blockIdx.y * 128;

  f4_t acc[4][4];
#pragma unroll
  for (int i = 0; i < 4; ++i)
#pragma unroll
    for (int j = 0; j < 4; ++j) acc[i][j] = (f4_t){0.f, 0.f, 0.f, 0.f};

  for (int kt = 0; kt < 256; kt += 64) {
    // stage A,B tiles: linear LDS dest, inverse-XOR-swizzled global source (rule #21)
#pragma unroll
    for (int it = 0; it < 4; ++it) {
      int idx = it * 256 + tid;        // 16B units
      int row = idx >> 3;
      int gslot = (idx & 7) ^ (row & 7);
      int grow = m0 + row; if (grow > M - 1) grow = M - 1;
      __builtin_amdgcn_global_load_lds(
          (const __attribute__((address_space(1))) unsigned int*)(A + (size_t)grow * 256 + kt + gslot * 8),
          (__attribute__((address_space(3))) unsigned int*)(As + idx * 8), 16, 0, 0);
    }
#pragma unroll
    for (int it = 0; it < 4; ++it) {
      int idx = it * 256 + tid;
      int row = idx >> 3;
      int gslot = (idx & 7) ^ (row & 7);
      __builtin_amdgcn_global_load_lds(
          (const __attribute__((address_space(1))) unsigned int*)(W + (size_t)(lbase + n0 + row) * 256 + kt + gslot * 8),
          (__attribute__((address_space(3))) unsigned int*)(Bs + idx * 8), 16, 0, 0);
    }
    asm volatile("s_waitcnt vmcnt(0)" ::: "memory");
    __syncthreads();
#pragma unroll
    for (int kk = 0; kk < 2; ++kk) {
      bf8_t af[4], bfv[4];
#pragma unroll
      for (int i = 0; i < 4; ++i) {
        int arow = wm * 64 + i * 16 + (lane & 15);
        int aslot = (kk * 4 + (lane >> 4)) ^ (arow & 7);
        af[i] = *(const bf8_t*)(As + arow * 64 + aslot * 8);
        int brow = wn * 64 + i * 16 + (lane & 15);
        int bslot = (kk * 4 + (lane >> 4)) ^ (brow & 7);
        bfv[i] = *(const bf8_t*)(Bs + brow * 64 + bslot * 8);
      }
#pragma unroll
      for (int i = 0; i < 4; ++i)
#pragma unroll
        for (int j = 0; j < 4; ++j)
          acc[i][j] = __builtin_amdgcn_mfma_f32_16x16x32_bf16(af[i], bfv[j], acc[i][j], 0, 0, 0);
    }
    __syncthreads();
  }
  // epilogue: C/D map row=(lane>>4)*4+r, col=lane&15 (m89), remap col->gate layout
#pragma unroll
  for (int i = 0; i < 4; ++i) {
#pragma unroll
    for (int j = 0; j < 4; ++j) {
      int col = n0 + wn * 64 + j * 16 + (lane & 15);
      float bv = bsum[lbase + col];
      int d_ = col >> 9, gate_ = (col >> 7) & 3, q_ = col & 127;
      int ncol = d_ * 512 + q_ * 4 + gate_;
#pragma unroll
      for (int r = 0; r < 4; ++r) {
        int row = m0 + wm * 64 + i * 16 + (lane >> 4) * 4 + r;
        if (row < M) C[(size_t)row * 1024 + ncol] = (__half)(acc[i][j][r] + bv);
      }
    }
  }
}

// ---------------- recurrence: one workgroup (4 waves) per (seq, dir) chain ----------------
#if defined(__has_builtin)
#if __has_builtin(__builtin_amdgcn_fdot2)
#define HAVE_FDOT2 1
#endif
#endif

static __device__ __forceinline__ float fdot2(h2_t a, h2_t b, float c) {
#ifdef HAVE_FDOT2
  return __builtin_amdgcn_fdot2(a, b, c, false);
#else
  return c + (float)a[0] * (float)b[0] + (float)a[1] * (float)b[1];
#endif
}
// v_rcp_f32-based activations (~1 ulp; avoids IEEE divide expansion)
static __device__ __forceinline__ float rcp_(float x) { return __builtin_amdgcn_rcpf(x); }
static __device__ __forceinline__ float sigm(float x) { return rcp_(1.f + __expf(-x)); }
static __device__ __forceinline__ float tanh_(float x) { return 1.f - 2.f * rcp_(1.f + __expf(2.f * x)); }

template <int LAYER>
__global__ __launch_bounds__(256) void k_rec(
    const __half* __restrict__ gates,     // (TOTAL,1024): [tok][d*512 + q*4 + gate]
    const int* __restrict__ offsets,      // (T,)
    const int* __restrict__ lengths,      // (NB,)
    const float* __restrict__ h0,         // (4,NB,CELL)
    const float* __restrict__ c0,
    const float* __restrict__ Whh,        // (4,512,128) f32
    unsigned short* __restrict__ y1,      // (TOTAL,256) bf16 (LAYER==0)
    float* __restrict__ outp,             // (TOTAL,256) f32  (LAYER==1)
    float* __restrict__ hn, float* __restrict__ cn,
    int T) {
  const int b = blockIdx.x >> 1;
  const int d = blockIdx.x & 1;
  const int k = 2 * LAYER + d;
  const int tid = threadIdx.x;
  const int lane = tid & 63;
  const int wave = tid >> 6;
  const int q = wave * 32 + (lane & 31);  // cell 0..127; each wave owns 32 cells
  const int s = lane >> 5;                // k-slice 0..1 (64 k each)
  const int L = lengths[b];

  __shared__ __align__(16) __half hb[2][CELL];  // ping-pong h
  __shared__ int toks[1024];

  for (int t = tid; t < T; t += 256) toks[t] = offsets[t] + b;

  // Per-thread weights: gate rows {q,128+q,256+q,384+q}, k in [64s, 64s+64), f16 pairs.
  h2_t wp[4][32];
  {
    const float* Wb = Whh + (size_t)k * GATES * CELL;
#pragma unroll
    for (int gi = 0; gi < 4; ++gi) {
      const float2* rowp = (const float2*)(Wb + (size_t)(gi * CELL + q) * CELL + s * 64);
#pragma unroll
      for (int j = 0; j < 32; ++j) {
        float2 w = rowp[j];
        h2_t pr; pr[0] = (_Float16)w.x; pr[1] = (_Float16)w.y;
        wp[gi][j] = pr;
      }
    }
  }

  float hcur = h0[(size_t)k * NB * CELL + b * CELL + q];
  float ccur = c0[(size_t)k * NB * CELL + b * CELL + q];
  if (s == 0) hb[0][q] = (__half)hcur;
  barrier_lds();   // toks + initial h visible (weight loads need no drain)

  const __half* gbase = gates + (size_t)d * 512 + (size_t)q * 4;
  auto tok_at = [&](int m) { int mm = (m < L) ? m : (L - 1); return toks[d ? (L - 1 - mm) : mm]; };
  auto gload = [&](int m) { return *(const uint2*)(gbase + (size_t)tok_at(m) * 1024); };

  // distance-2 prefetch into two statically named slots (no register copies)
  uint2 gA = (L > 0) ? gload(0) : make_uint2(0, 0);
  uint2 gB = (L > 1) ? gload(1) : gA;

  int p = 0;
  auto body = [&](int n, uint2& gcur) {
    // dot stage: 4 gates x 64 k, two 16-deep chains per gate
    const h2_t* hsh = (const h2_t*)(&hb[p][0]) + s * 32;
    h2_t hp[32];
#pragma unroll
    for (int j = 0; j < 32; ++j) hp[j] = hsh[j];
    float x00 = 0.f, x01 = 0.f, x10 = 0.f, x11 = 0.f;
    float x20 = 0.f, x21 = 0.f, x30 = 0.f, x31 = 0.f;
#pragma unroll
    for (int j = 0; j < 16; ++j) {
      x00 = fdot2(wp[0][j], hp[j], x00); x01 = fdot2(wp[0][j + 16], hp[j + 16], x01);
      x10 = fdot2(wp[1][j], hp[j], x10); x11 = fdot2(wp[1][j + 16], hp[j + 16], x11);
      x20 = fdot2(wp[2][j], hp[j], x20); x21 = fdot2(wp[2][j + 16], hp[j + 16], x21);
      x30 = fdot2(wp[3][j], hp[j], x30); x31 = fdot2(wp[3][j + 16], hp[j + 16], x31);
    }
    float f0 = x00 + x01, f1 = x10 + x11, f2 = x20 + x21, f3 = x30 + x31;
    // single-stage reduce across the 2 k-slices (lanes l <-> l^32)
    f0 += __shfl_xor(f0, 32, 64);
    f1 += __shfl_xor(f1, 32, 64);
    f2 += __shfl_xor(f2, 32, 64);
    f3 += __shfl_xor(f3, 32, 64);

    // epilogue (replicated on both slice lanes, branch-free)
    union { uint2 u; __half h[4]; } gg; gg.u = gcur;
    float vi = f0 + (float)gg.h[0];
    float vf = f1 + (float)gg.h[1];
    float vg = f2 + (float)gg.h[2];
    float vo = f3 + (float)gg.h[3];
    float fi = sigm(vi), ff = sigm(vf), fg = tanh_(vg), fo = sigm(vo);
    ccur = ff * ccur + fi * fg;
    hcur = fo * tanh_(ccur);

    int tokc = tok_at(n);
    if (s == 0) {
      hb[p ^ 1][q] = (__half)hcur;
      if (LAYER == 0)
        y1[(size_t)tokc * 256 + d * CELL + q] = f32_bf16(hcur);
      else
        outp[(size_t)tokc * 256 + d * CELL + q] = hcur;
    }
    // prefetch step n+2 into the slot just consumed; stays in flight ACROSS the
    // raw barrier (no vmcnt drain) — consumed ~2 steps after issue.
    gcur = gload(n + 2);
    barrier_lds();   // new h visible; hb[p] reads done (lgkm only, no vmcnt)
    p ^= 1;
  };

  int n = 0;
  while (n + 1 < L) { body(n, gA); body(n + 1, gB); n += 2; }
  if (n < L) body(n, gA);

  if (s == 0) {
    hn[(size_t)k * NB * CELL + b * CELL + q] = hcur;
    cn[(size_t)k * NB * CELL + b * CELL + q] = ccur;
  }
}

// ---------------- launch ----------------
extern "C" void kernel_launch(void* const* d_in, const int* in_sizes, int n_in,
                              void* d_out, int out_size, void* d_ws, size_t ws_size,
                              hipStream_t stream) {
  const float* x   = (const float*)d_in[0];
  const int*   bs  = (const int*)d_in[1];
  const float* h0  = (const float*)d_in[2];
  const float* c0  = (const float*)d_in[3];
  const float* wih = (const float*)d_in[4];
  const float* whh = (const float*)d_in[5];
  const float* bih = (const float*)d_in[6];
  const float* bhh = (const float*)d_in[7];
  const int TOTAL = in_sizes[0] / DIN;
  const int T = in_sizes[1];

  char* ws = (char*)d_ws;
  size_t off = 0;
  auto alloc = [&](size_t bytes) {
    void* p = ws + off;
    off = (off + bytes + 255) & ~(size_t)255;
    return p;
  };
  int* offsets        = (int*)alloc((size_t)T * 4);
  int* lengths        = (int*)alloc(NB * 4);
  float* bsum         = (float*)alloc(2048 * 4);
  unsigned short* wb  = (unsigned short*)alloc((size_t)2048 * 256 * 2);
  unsigned short* xb  = (unsigned short*)alloc((size_t)TOTAL * 256 * 2);
  unsigned short* y1  = (unsigned short*)alloc((size_t)TOTAL * 256 * 2);
  __half* gates       = (__half*)alloc((size_t)TOTAL * 1024 * 2);
  // total ~153 MB; assumed <= ws_size

  float* outp = (float*)d_out;
  float* hn = outp + (size_t)TOTAL * 256;
  float* cn = hn + 4 * NB * CELL;

  k_setup<<<1, 1024, 0, stream>>>(bs, T, offsets, lengths);
  k_convert<<<1024, 256, 0, stream>>>(x, xb, TOTAL * 256,
                                      wih, wb, 4 * GATES * DIN,
                                      bih, bhh, bsum, 2048);
  dim3 ggrid((TOTAL + 127) / 128, 8);
  // layer 0
  k_gemm<<<ggrid, 256, 0, stream>>>(xb, wb, bsum, gates, TOTAL, 0);
  k_rec<0><<<NB * 2, 256, 0, stream>>>(gates, offsets, lengths, h0, c0, whh,
                                       y1, nullptr, hn, cn, T);
  // layer 1
  k_gemm<<<ggrid, 256, 0, stream>>>(y1, wb, bsum, gates, TOTAL, 1024);
  k_rec<1><<<NB * 2, 256, 0, stream>>>(gates, offsets, lengths, h0, c0, whh,
                                       nullptr, outp, hn, cn, T);
}